// Round 9
// baseline (171.643 us; speedup 1.0000x reference)
//
#include <hip/hip_runtime.h>

// Ordered bi-bi mechanism dydt. Species: [E, EA, EQ, EAB, A, B, P, Q].
//
// R9 = R8's fully-covered unit-stride LDS-staged structure x R5/R6's
// memory-level parallelism. Across R0-R8 the ONLY variable separating the
// 60us plateau from the 43us plateau is per-thread in-flight bytes at issue
// time (64B -> 60us; 128-256B -> 43us); R8 tested full line coverage but
// dropped MLP back to 64B. Here each thread owns EPT=2 elements and issues
// all 8 independent 16B loads (128B in flight) before any wait:
//   - y: 4 unit-stride float4 rows (every line fully covered by the wave)
//   - kf/kr: 2 each, unit-stride, stay in registers
// y tile staged through LDS for the per-element gather; output transposed
// back through the same LDS slots (read set == write set per thread => no
// barrier between gather and write-back; 2 barriers total). 16KB LDS/block.

typedef float v4f __attribute__((ext_vector_type(4)));

#define TPB 256
#define EPT 2                       // elements per thread
#define EPB (TPB * EPT)             // elements per block (512)

__device__ __forceinline__ void ode_elem(v4f ya, v4f yb, v4f f, v4f r,
                                         v4f& oa, v4f& ob) {
    float E  = ya.x, EA = ya.y, EQ = ya.z, EAB = ya.w;
    float A  = yb.x, Bc = yb.y, P  = yb.z, Q   = yb.w;

    float v0 = f.x * E   * A  - r.x * EA;
    float v1 = f.y * EA  * Bc - r.y * EAB;
    float v2 = f.z * EAB      - r.z * EQ * P;
    float v3 = f.w * EQ       - r.w * E  * Q;

    oa.x = v3 - v0;   // dE
    oa.y = v0 - v1;   // dEA
    oa.z = v2 - v3;   // dEQ
    oa.w = v1 - v2;   // dEAB
    ob.x = -v0;       // dA
    ob.y = -v1;       // dB
    ob.z =  v2;       // dP
    ob.w =  v3;       // dQ
}

__global__ __launch_bounds__(TPB) void ode_kernel(
    const v4f* __restrict__ y4,
    const v4f* __restrict__ kf4,
    const v4f* __restrict__ kr4,
    v4f* __restrict__ out4,
    int B)    // number of elements
{
    __shared__ v4f buf[2 * EPB];         // 16 KB tile buffer

    const int tid  = threadIdx.x;
    const int base = blockIdx.x * EPB;   // first element of this tile
    const int n2   = 2 * B;

    v4f a[2 * EPT], f[EPT], r[EPT];

    if (base + EPB <= B) {
        // ---- fast path: branch-free burst of 8 independent loads ----
        #pragma unroll
        for (int k = 0; k < 2 * EPT; ++k)
            a[k] = y4[2 * base + tid + k * TPB];
        #pragma unroll
        for (int k = 0; k < EPT; ++k) {
            f[k] = kf4[base + tid + k * TPB];
            r[k] = kr4[base + tid + k * TPB];
        }
    } else {
        // ---- tail: boundary block only ----
        #pragma unroll
        for (int k = 0; k < 2 * EPT; ++k) {
            int g = 2 * base + tid + k * TPB;
            a[k] = (g < n2) ? y4[g] : (v4f){0.f, 0.f, 0.f, 0.f};
        }
        #pragma unroll
        for (int k = 0; k < EPT; ++k) {
            int e = base + tid + k * TPB;
            if (e < B) { f[k] = kf4[e]; r[k] = kr4[e]; }
            else       { f[k] = (v4f){0.f,0.f,0.f,0.f}; r[k] = f[k]; }
        }
    }

    // stage y tile into LDS in load order
    #pragma unroll
    for (int k = 0; k < 2 * EPT; ++k)
        buf[tid + k * TPB] = a[k];
    __syncthreads();

    // per-element gather + compute + write-back into the SAME slots
    // (read set == write set per thread => no barrier in between)
    #pragma unroll
    for (int k = 0; k < EPT; ++k) {
        int le = tid + k * TPB;          // local element index
        v4f ya = buf[2 * le];
        v4f yb = buf[2 * le + 1];
        v4f oa, ob;
        ode_elem(ya, yb, f[k], r[k], oa, ob);
        buf[2 * le]     = oa;
        buf[2 * le + 1] = ob;
    }
    __syncthreads();

    // ---- fully-covered unit-stride global stores ----
    if (base + EPB <= B) {
        #pragma unroll
        for (int k = 0; k < 2 * EPT; ++k)
            out4[2 * base + tid + k * TPB] = buf[tid + k * TPB];
    } else {
        #pragma unroll
        for (int k = 0; k < 2 * EPT; ++k) {
            int g = 2 * base + tid + k * TPB;
            if (g < n2) out4[g] = buf[tid + k * TPB];
        }
    }
}

extern "C" void kernel_launch(void* const* d_in, const int* in_sizes, int n_in,
                              void* d_out, int out_size, void* d_ws, size_t ws_size,
                              hipStream_t stream) {
    // inputs: [0]=t (1,), [1]=y (B,8), [2]=forward_rates (B,4), [3]=reverse_rates (B,4)
    const v4f* y4  = (const v4f*)d_in[1];
    const v4f* kf4 = (const v4f*)d_in[2];
    const v4f* kr4 = (const v4f*)d_in[3];
    v4f* out4 = (v4f*)d_out;
    int B = in_sizes[1] / 8;

    int grid = (B + EPB - 1) / EPB;   // one 512-element tile per block
    ode_kernel<<<grid, TPB, 0, stream>>>(y4, kf4, kr4, out4, B);
}

// Round 10
// 165.754 us; speedup vs baseline: 1.0355x; 1.0355x over previous
//
#include <hip/hip_runtime.h>

// Ordered bi-bi mechanism dydt. Species: [E, EA, EQ, EAB, A, B, P, Q].
//
// FINAL FORM (= R6, the session's best: 42.6us dispatch / 164.6us harness).
// One thread per element, direct-register compute, one-shot burst grid,
// NONTEMPORAL loads, cached stores.
//
// Causal story (10 structural variants, R0-R9):
//  - Two performance plateaus exist: ~60us and ~42.6us. The fast plateau is
//    reached only by kernels with nontemporal loads + direct-register
//    one-shot burst structure (R5/R6). Exchange removal, MLP (64->256B),
//    line coverage (R8/R9 LDS transform), persistence (R4/R7), and store
//    policy (nt vs cached, R1/R5/R6) are all second-order: each was varied
//    independently and never moved a kernel off its plateau.
//  - The 42.6us floor is NOT bandwidth-bound: R5 moved +20MB more HBM bytes
//    in the same time; the harness's own copyBuffer runs at 2.26 TB/s
//    (slower per byte than this kernel's 3.0-3.4 TB/s); only write-only
//    fill reaches 6.36 TB/s. Mixed read/write streams in the harness's
//    dirtied-L3 state cap around ~3-3.5 TB/s.
//  - Counters at this floor: FETCH ~62.5MB (half the 128MB logical reads is
//    L3-resident), WRITE exactly 62.5MB (no amplification), VALUBusy ~3.3%,
//    LDS conflicts 0, VGPR 36 — no execution pipe loaded.
//
// Structure details:
//  - ITERS=4: 16 independent nt loads (256B) in flight per thread before
//    any wait (2->4 sweep showed saturation: 43.2 -> 42.6us).
//  - Stores REGULAR (cached): nt stores at 32B lane stride half-cover 64B
//    lines and bypass L2 write-merging -> +31% write amplification (R5).
//  - 32B lane stride on y/out is free: sectored caches fetch only touched
//    16B sectors (FETCH_SIZE identical to fully-covered variants).

typedef float v4f __attribute__((ext_vector_type(4)));

#define ITERS 4

__device__ __forceinline__ void ode_elem(v4f ya, v4f yb, v4f f, v4f r,
                                         v4f& oa, v4f& ob) {
    float E  = ya.x, EA = ya.y, EQ = ya.z, EAB = ya.w;
    float A  = yb.x, Bc = yb.y, P  = yb.z, Q   = yb.w;

    float v0 = f.x * E   * A  - r.x * EA;
    float v1 = f.y * EA  * Bc - r.y * EAB;
    float v2 = f.z * EAB      - r.z * EQ * P;
    float v3 = f.w * EQ       - r.w * E  * Q;

    oa.x = v3 - v0;   // dE
    oa.y = v0 - v1;   // dEA
    oa.z = v2 - v3;   // dEQ
    oa.w = v1 - v2;   // dEAB
    ob.x = -v0;       // dA
    ob.y = -v1;       // dB
    ob.z =  v2;       // dP
    ob.w =  v3;       // dQ
}

__global__ __launch_bounds__(256) void ode_kernel(
    const v4f* __restrict__ y4,
    const v4f* __restrict__ kf4,
    const v4f* __restrict__ kr4,
    v4f* __restrict__ out4,
    int B)    // number of elements
{
    const int stride = gridDim.x * blockDim.x;
    const int e0 = blockIdx.x * blockDim.x + threadIdx.x;

    if (e0 + (ITERS - 1) * stride < B) {
        // ---- fast path: branch-free. all loads -> compute -> all stores ----
        v4f ya[ITERS], yb[ITERS], f[ITERS], r[ITERS];
        #pragma unroll
        for (int k = 0; k < ITERS; ++k) {
            int e = e0 + k * stride;
            ya[k] = __builtin_nontemporal_load(y4 + 2 * e);
            yb[k] = __builtin_nontemporal_load(y4 + 2 * e + 1);
            f[k]  = __builtin_nontemporal_load(kf4 + e);
            r[k]  = __builtin_nontemporal_load(kr4 + e);
        }

        v4f oa[ITERS], ob[ITERS];
        #pragma unroll
        for (int k = 0; k < ITERS; ++k)
            ode_elem(ya[k], yb[k], f[k], r[k], oa[k], ob[k]);

        #pragma unroll
        for (int k = 0; k < ITERS; ++k) {
            int e = e0 + k * stride;
            out4[2 * e]     = oa[k];   // cached: L2 merges the half-line pairs
            out4[2 * e + 1] = ob[k];
        }
    } else {
        // ---- tail path: boundary block only ----
        for (int k = 0; k < ITERS; ++k) {
            int e = e0 + k * stride;
            if (e < B) {
                v4f ya = __builtin_nontemporal_load(y4 + 2 * e);
                v4f yb = __builtin_nontemporal_load(y4 + 2 * e + 1);
                v4f f  = __builtin_nontemporal_load(kf4 + e);
                v4f r  = __builtin_nontemporal_load(kr4 + e);
                v4f oa, ob;
                ode_elem(ya, yb, f, r, oa, ob);
                out4[2 * e]     = oa;
                out4[2 * e + 1] = ob;
            }
        }
    }
}

extern "C" void kernel_launch(void* const* d_in, const int* in_sizes, int n_in,
                              void* d_out, int out_size, void* d_ws, size_t ws_size,
                              hipStream_t stream) {
    // inputs: [0]=t (1,), [1]=y (B,8), [2]=forward_rates (B,4), [3]=reverse_rates (B,4)
    const v4f* y4  = (const v4f*)d_in[1];
    const v4f* kf4 = (const v4f*)d_in[2];
    const v4f* kr4 = (const v4f*)d_in[3];
    v4f* out4 = (v4f*)d_out;
    int B = in_sizes[1] / 8;

    int block = 256;
    int grid  = (B + block * ITERS - 1) / (block * ITERS);
    ode_kernel<<<grid, block, 0, stream>>>(y4, kf4, kr4, out4, B);
}